// Round 6
// baseline (86.882 us; speedup 1.0000x reference)
//
#include <hip/hip_runtime.h>
#include <math.h>
#include <stdint.h>

// p=2, j=32, k=32, m=32, l=8, n=32; B=2048 rows; K=1024 (=k*n); N=1024 (=j*m).
//
// out[b, jm] = s * sum_kn q[b,kn] * Wt[jm, kn] + bias[jm]
//   q = clip(rint(x/s), +-127)   (small integer -> exact in bf16)
//   Wt[(j,m),(k,n)] = sum_p a0*sY*sZ*W[m,n] + a1*sY*Ysum[m] + a2*sZ*Zcol[n] + a3
//   W[m,n] = 8 - 2*popc(Sy[m]^Sz[n])  (sign-bit masks over l)

typedef __attribute__((ext_vector_type(8))) short bf16x8;
typedef __attribute__((ext_vector_type(4))) float f32x4;
typedef __attribute__((ext_vector_type(4))) unsigned short us4;

__device__ __forceinline__ unsigned short f2bf(float f) {
    union { float f; uint32_t u; } c; c.f = f;
    uint32_t r = 0x7fffu + ((c.u >> 16) & 1u);
    return (unsigned short)((c.u + r) >> 16);
}

__device__ __forceinline__ void gl2lds16(const void* g, void* l) {
    __builtin_amdgcn_global_load_lds(
        (const __attribute__((address_space(1))) void*)g,
        (__attribute__((address_space(3))) void*)l, 16, 0, 0);
}

// ---------------------------------------------------------------------------
// Fused: blocks [0,1024) -> one (j,k) tile of Wt via ballot/popcount;
//        blocks [1024,1536) -> quantize x -> qx.   (unchanged from r5)
__global__ __launch_bounds__(256) void fused_pre(
    const float* __restrict__ Y,     // (2,32,32,32,8)
    const float* __restrict__ Z,     // (2,32,32,8,32)
    const float* __restrict__ A,     // (2,32,32,4)
    const float* __restrict__ x,     // (2048,1024)
    const float* __restrict__ act_scale,
    unsigned short* __restrict__ wt, // (1024 N, 1024 K) bf16 bits
    unsigned short* __restrict__ qx) // (2048,1024) bf16 bits
{
    const int t = threadIdx.x;

    if (blockIdx.x >= 1024) {
        const float s = fmaxf(fabsf(act_scale[0]), 1e-8f);
        const int b2 = blockIdx.x - 1024;
        #pragma unroll
        for (int it = 0; it < 4; ++it) {
            const size_t i4 = (size_t)b2 * 256 + t + (size_t)it * 131072;
            const float4 v = *(const float4*)(x + i4 * 4);
            us4 o;
            o.x = f2bf(fminf(fmaxf(rintf(v.x / s), -127.f), 127.f));
            o.y = f2bf(fminf(fmaxf(rintf(v.y / s), -127.f), 127.f));
            o.z = f2bf(fminf(fmaxf(rintf(v.z / s), -127.f), 127.f));
            o.w = f2bf(fminf(fmaxf(rintf(v.w / s), -127.f), 127.f));
            *(us4*)(qx + i4 * 4) = o;
        }
        return;
    }

    __shared__ unsigned int yb[2][8];   // [p][word]: byte b of word pair = Sy[m]
    __shared__ unsigned int zb[2][8];   // [p][l]: bit n = sign Z[l][n]
    __shared__ float wred[16];

    const int jk = blockIdx.x;
    const int jj = jk >> 5;
    const int kk = jk & 31;
    const int n  = t & 31;
    const int mb = t >> 5;      // 0..7
    const int w  = t >> 6;
    const int lane = t & 63;

    const int base0 = jj * 32 + kk;
    const int base1 = 1024 + base0;

    const float yv0 = Y[(size_t)base0 * 256 + t];
    const float yv1 = Y[(size_t)base1 * 256 + t];
    const float zv0 = Z[(size_t)base0 * 256 + t];
    const float zv1 = Z[(size_t)base1 * 256 + t];
    const float a00 = A[(size_t)base0 * 4 + 0], a01 = A[(size_t)base0 * 4 + 1];
    const float a02 = A[(size_t)base0 * 4 + 2], a03 = A[(size_t)base0 * 4 + 3];
    const float a10 = A[(size_t)base1 * 4 + 0], a11 = A[(size_t)base1 * 4 + 1];
    const float a12 = A[(size_t)base1 * 4 + 2], a13 = A[(size_t)base1 * 4 + 3];

    const unsigned long long by0 = __ballot(yv0 < 0.f);
    const unsigned long long by1 = __ballot(yv1 < 0.f);
    const unsigned long long bz0 = __ballot(zv0 < 0.f);
    const unsigned long long bz1 = __ballot(zv1 < 0.f);
    if (lane == 0) {
        yb[0][2 * w] = (unsigned)by0; yb[0][2 * w + 1] = (unsigned)(by0 >> 32);
        yb[1][2 * w] = (unsigned)by1; yb[1][2 * w + 1] = (unsigned)(by1 >> 32);
        zb[0][2 * w] = (unsigned)bz0; zb[0][2 * w + 1] = (unsigned)(bz0 >> 32);
        zb[1][2 * w] = (unsigned)bz1; zb[1][2 * w + 1] = (unsigned)(bz1 >> 32);
    }

    float ay0 = fabsf(yv0), az0 = fabsf(zv0);
    float ay1 = fabsf(yv1), az1 = fabsf(zv1);
    #pragma unroll
    for (int d = 1; d < 64; d <<= 1) {
        ay0 += __shfl_xor(ay0, d, 64);
        az0 += __shfl_xor(az0, d, 64);
        ay1 += __shfl_xor(ay1, d, 64);
        az1 += __shfl_xor(az1, d, 64);
    }
    if (lane == 0) {
        wred[w * 4 + 0] = ay0;
        wred[w * 4 + 1] = az0;
        wred[w * 4 + 2] = ay1;
        wred[w * 4 + 3] = az1;
    }
    __syncthreads();

    const float sY0 = (wred[0] + wred[4] + wred[8]  + wred[12]) * (1.f / 256.f);
    const float sZ0 = (wred[1] + wred[5] + wred[9]  + wred[13]) * (1.f / 256.f);
    const float sY1 = (wred[2] + wred[6] + wred[10] + wred[14]) * (1.f / 256.f);
    const float sZ1 = (wred[3] + wred[7] + wred[11] + wred[15]) * (1.f / 256.f);

    const float c00 = a00 * sY0 * sZ0, c01 = a01 * sY0, c02 = a02 * sZ0;
    const float c10 = a10 * sY1 * sZ1, c11 = a11 * sY1, c12 = a12 * sZ1;
    const float cb  = a03 + a13;

    unsigned sz0 = 0, sz1 = 0;
    #pragma unroll
    for (int l = 0; l < 8; ++l) {
        sz0 |= ((zb[0][l] >> n) & 1u) << l;
        sz1 |= ((zb[1][l] >> n) & 1u) << l;
    }
    const float zc0 = 8.f - 2.f * (float)__popc(sz0);
    const float zc1 = 8.f - 2.f * (float)__popc(sz1);
    const float czc = c02 * zc0 + c12 * zc1 + cb;

    const int ybw = (mb >> 2);
    const int ybs = (mb & 3) * 8;

    #pragma unroll
    for (int q = 0; q < 4; ++q) {
        const int m = mb + 8 * q;
        const unsigned sy0 = (yb[0][2 * q + ybw] >> ybs) & 0xffu;
        const unsigned sy1 = (yb[1][2 * q + ybw] >> ybs) & 0xffu;
        const float w0  = 8.f - 2.f * (float)__popc(sy0 ^ sz0);
        const float w1  = 8.f - 2.f * (float)__popc(sy1 ^ sz1);
        const float ys0 = 8.f - 2.f * (float)__popc(sy0);
        const float ys1 = 8.f - 2.f * (float)__popc(sy1);
        const float acc = c00 * w0 + c01 * ys0 + c10 * w1 + c11 * ys1 + czc;
        wt[(size_t)(jj * 32 + m) * 1024 + kk * 32 + n] = f2bf(acc);
    }
}

// ---------------------------------------------------------------------------
// GEMM (m97 shape): out[2048,1024] = s * (Q x Wt^T) + bias
// 128(M) x 128(N) tile, grid (8,16)=128 blocks, 4 waves 2x2, each wave a
// 64x64 accumulator (4x4 frags of 16x16x32 -> 32 FLOP per LDS byte).
// BK=64, double-buffered LDS (2 x 32KB), XOR-swizzled 16B chunks:
//   chunk (row, kc) lives at row*8 + (kc ^ (row&7))  -> conflict-free b128.
__global__ __launch_bounds__(256) void gemm_mfma(
    const unsigned short* __restrict__ qx,   // (2048,1024) bf16 bits
    const unsigned short* __restrict__ wt,   // (1024 N,1024 K) bf16 bits
    const float* __restrict__ bias,          // (1024)
    const float* __restrict__ act_scale,     // (1)
    float* __restrict__ out)                 // (2048,1024)
{
    // buffer = A 128x64 (16KB) + B 128x64 (16KB); double buffered = 64KB
    __shared__ __align__(16) short lds[2 * 16384];

    const int tid  = threadIdx.x;
    const int lane = tid & 63;
    const int wave = tid >> 6;
    const int wm = wave >> 1;
    const int wn = wave & 1;
    const int rowBase = blockIdx.y * 128;
    const int colBase = blockIdx.x * 128;

    const float s = fmaxf(fabsf(act_scale[0]), 1e-8f);

    f32x4 acc[4][4];
    #pragma unroll
    for (int i = 0; i < 4; ++i)
        #pragma unroll
        for (int jx = 0; jx < 4; ++jx)
            acc[i][jx] = (f32x4)0.f;

    // staging: panel = 128 rows x 8 chunks (16B). chunk c = g*64 + lane,
    // g = it*4 + wave (it 0..3). row = g*8 + (lane>>3), kc_global = (lane&7)^(lane>>3).
    const int lr = lane >> 3;
    const int kx = (lane & 7) ^ lr;
    const unsigned short* ag[4];
    const unsigned short* bg[4];
    #pragma unroll
    for (int it = 0; it < 4; ++it) {
        const int g = it * 4 + wave;          // 0..15
        ag[it] = qx + (size_t)(rowBase + g * 8 + lr) * 1024 + kx * 8;
        bg[it] = wt + (size_t)(colBase + g * 8 + lr) * 1024 + kx * 8;
    }

    char* const ldsc = (char*)lds;
    const int q4  = lane >> 4;
    const int l16 = lane & 15;

    // prologue: stage tile 0 into buffer 0
    #pragma unroll
    for (int it = 0; it < 4; ++it) {
        const int g = it * 4 + wave;
        gl2lds16(ag[it], ldsc + g * 1024);
        gl2lds16(bg[it], ldsc + 16384 + g * 1024);
    }

    for (int kt = 0; kt < 16; ++kt) {
        __syncthreads();   // buffer kt&1 ready (drains prev prefetch too)

        if (kt + 1 < 16) {
            const int k1 = (kt + 1) * 64;
            char* bb = ldsc + ((kt + 1) & 1) * 32768;
            #pragma unroll
            for (int it = 0; it < 4; ++it) {
                const int g = it * 4 + wave;
                gl2lds16(ag[it] + k1, bb + g * 1024);
                gl2lds16(bg[it] + k1, bb + 16384 + g * 1024);
            }
        }

        const short* As = lds + (kt & 1) * 16384;   // [row][8 chunks] swizzled
        const short* Bs = As + 8192;

        #pragma unroll
        for (int k2 = 0; k2 < 2; ++k2) {
            const int kc = k2 * 4 + q4;            // chunk slot 0..7
            bf16x8 af[4], bfr[4];
            #pragma unroll
            for (int im = 0; im < 4; ++im) {
                const int r = wm * 64 + im * 16 + l16;
                af[im] = *(const bf16x8*)&As[r * 64 + ((kc ^ (r & 7)) << 3)];
            }
            #pragma unroll
            for (int in = 0; in < 4; ++in) {
                const int r = wn * 64 + in * 16 + l16;
                bfr[in] = *(const bf16x8*)&Bs[r * 64 + ((kc ^ (r & 7)) << 3)];
            }
            #pragma unroll
            for (int im = 0; im < 4; ++im)
                #pragma unroll
                for (int in = 0; in < 4; ++in)
                    acc[im][in] = __builtin_amdgcn_mfma_f32_16x16x32_bf16(
                        af[im], bfr[in], acc[im][in], 0, 0, 0);
        }
    }

    // epilogue: C/D layout col = lane&15, row = quad*4 + reg
    #pragma unroll
    for (int im = 0; im < 4; ++im) {
        #pragma unroll
        for (int in = 0; in < 4; ++in) {
            const int col = colBase + wn * 64 + in * 16 + l16;
            const float b = bias[col];
            #pragma unroll
            for (int r = 0; r < 4; ++r) {
                const int row = rowBase + wm * 64 + im * 16 + q4 * 4 + r;
                out[(size_t)row * 1024 + col] = s * acc[im][in][r] + b;
            }
        }
    }
}

extern "C" void kernel_launch(void* const* d_in, const int* in_sizes, int n_in,
                              void* d_out, int out_size, void* d_ws, size_t ws_size,
                              hipStream_t stream) {
    const float* x         = (const float*)d_in[0];  // (2,1024,1024)
    const float* Y_fp      = (const float*)d_in[1];  // (2,32,32,32,8)
    const float* Z_fp      = (const float*)d_in[2];  // (2,32,32,8,32)
    const float* A         = (const float*)d_in[3];  // (2,32,32,4)
    const float* bias      = (const float*)d_in[4];  // (1024)
    const float* act_scale = (const float*)d_in[5];  // (1)
    float* out = (float*)d_out;                      // (2048,1024)

    unsigned short* wtp = (unsigned short*)d_ws;                            // 2 MB
    unsigned short* qxp = (unsigned short*)((char*)d_ws + 2 * 1024 * 1024); // 4 MB

    fused_pre<<<dim3(1536), dim3(256), 0, stream>>>(Y_fp, Z_fp, A, x, act_scale, wtp, qxp);
    gemm_mfma<<<dim3(8, 16), dim3(256), 0, stream>>>(qxp, wtp, bias, act_scale, out);
}

// Round 7
// 80.973 us; speedup vs baseline: 1.0730x; 1.0730x over previous
//
#include <hip/hip_runtime.h>
#include <math.h>
#include <stdint.h>

// p=2, j=32, k=32, m=32, l=8, n=32; B=2048 rows; K=1024 (=k*n); N=1024 (=j*m).
//
// out[b, jm] = s * sum_kn q[b,kn] * Wt[jm, kn] + bias[jm]
//   q = clip(rint(x/s), +-127)   (small integer -> exact in bf16)
//   Wt[(j,m),(k,n)] = sum_p a0*sY*sZ*W[m,n] + a1*sY*Ysum[m] + a2*sZ*Zcol[n] + a3
//   W[m,n] = 8 - 2*popc(Sy[m]^Sz[n])  (sign-bit masks over l)

typedef __attribute__((ext_vector_type(8))) short bf16x8;
typedef __attribute__((ext_vector_type(4))) float f32x4;
typedef __attribute__((ext_vector_type(4))) unsigned short us4;

__device__ __forceinline__ unsigned short f2bf(float f) {
    union { float f; uint32_t u; } c; c.f = f;
    uint32_t r = 0x7fffu + ((c.u >> 16) & 1u);
    return (unsigned short)((c.u + r) >> 16);
}

__device__ __forceinline__ void gl2lds16(const void* g, void* l) {
    __builtin_amdgcn_global_load_lds(
        (const __attribute__((address_space(1))) void*)g,
        (__attribute__((address_space(3))) void*)l, 16, 0, 0);
}

// ---------------------------------------------------------------------------
// Fused: blocks [0,1024) -> one (j,k) tile of Wt via ballot/popcount;
//        blocks [1024,1536) -> quantize x -> qx.   (unchanged from r5)
__global__ __launch_bounds__(256) void fused_pre(
    const float* __restrict__ Y,     // (2,32,32,32,8)
    const float* __restrict__ Z,     // (2,32,32,8,32)
    const float* __restrict__ A,     // (2,32,32,4)
    const float* __restrict__ x,     // (2048,1024)
    const float* __restrict__ act_scale,
    unsigned short* __restrict__ wt, // (1024 N, 1024 K) bf16 bits
    unsigned short* __restrict__ qx) // (2048,1024) bf16 bits
{
    const int t = threadIdx.x;

    if (blockIdx.x >= 1024) {
        const float s = fmaxf(fabsf(act_scale[0]), 1e-8f);
        const int b2 = blockIdx.x - 1024;
        #pragma unroll
        for (int it = 0; it < 4; ++it) {
            const size_t i4 = (size_t)b2 * 256 + t + (size_t)it * 131072;
            const float4 v = *(const float4*)(x + i4 * 4);
            us4 o;
            o.x = f2bf(fminf(fmaxf(rintf(v.x / s), -127.f), 127.f));
            o.y = f2bf(fminf(fmaxf(rintf(v.y / s), -127.f), 127.f));
            o.z = f2bf(fminf(fmaxf(rintf(v.z / s), -127.f), 127.f));
            o.w = f2bf(fminf(fmaxf(rintf(v.w / s), -127.f), 127.f));
            *(us4*)(qx + i4 * 4) = o;
        }
        return;
    }

    __shared__ unsigned int yb[2][8];   // [p][word]: packed sign(Y) bytes
    __shared__ unsigned int zb[2][8];   // [p][l]: bit n = sign Z[l][n]
    __shared__ float wred[16];

    const int jk = blockIdx.x;
    const int jj = jk >> 5;
    const int kk = jk & 31;
    const int n  = t & 31;
    const int mb = t >> 5;      // 0..7
    const int w  = t >> 6;
    const int lane = t & 63;

    const int base0 = jj * 32 + kk;
    const int base1 = 1024 + base0;

    const float yv0 = Y[(size_t)base0 * 256 + t];
    const float yv1 = Y[(size_t)base1 * 256 + t];
    const float zv0 = Z[(size_t)base0 * 256 + t];
    const float zv1 = Z[(size_t)base1 * 256 + t];
    const float a00 = A[(size_t)base0 * 4 + 0], a01 = A[(size_t)base0 * 4 + 1];
    const float a02 = A[(size_t)base0 * 4 + 2], a03 = A[(size_t)base0 * 4 + 3];
    const float a10 = A[(size_t)base1 * 4 + 0], a11 = A[(size_t)base1 * 4 + 1];
    const float a12 = A[(size_t)base1 * 4 + 2], a13 = A[(size_t)base1 * 4 + 3];

    const unsigned long long by0 = __ballot(yv0 < 0.f);
    const unsigned long long by1 = __ballot(yv1 < 0.f);
    const unsigned long long bz0 = __ballot(zv0 < 0.f);
    const unsigned long long bz1 = __ballot(zv1 < 0.f);
    if (lane == 0) {
        yb[0][2 * w] = (unsigned)by0; yb[0][2 * w + 1] = (unsigned)(by0 >> 32);
        yb[1][2 * w] = (unsigned)by1; yb[1][2 * w + 1] = (unsigned)(by1 >> 32);
        zb[0][2 * w] = (unsigned)bz0; zb[0][2 * w + 1] = (unsigned)(bz0 >> 32);
        zb[1][2 * w] = (unsigned)bz1; zb[1][2 * w + 1] = (unsigned)(bz1 >> 32);
    }

    float ay0 = fabsf(yv0), az0 = fabsf(zv0);
    float ay1 = fabsf(yv1), az1 = fabsf(zv1);
    #pragma unroll
    for (int d = 1; d < 64; d <<= 1) {
        ay0 += __shfl_xor(ay0, d, 64);
        az0 += __shfl_xor(az0, d, 64);
        ay1 += __shfl_xor(ay1, d, 64);
        az1 += __shfl_xor(az1, d, 64);
    }
    if (lane == 0) {
        wred[w * 4 + 0] = ay0;
        wred[w * 4 + 1] = az0;
        wred[w * 4 + 2] = ay1;
        wred[w * 4 + 3] = az1;
    }
    __syncthreads();

    const float sY0 = (wred[0] + wred[4] + wred[8]  + wred[12]) * (1.f / 256.f);
    const float sZ0 = (wred[1] + wred[5] + wred[9]  + wred[13]) * (1.f / 256.f);
    const float sY1 = (wred[2] + wred[6] + wred[10] + wred[14]) * (1.f / 256.f);
    const float sZ1 = (wred[3] + wred[7] + wred[11] + wred[15]) * (1.f / 256.f);

    const float c00 = a00 * sY0 * sZ0, c01 = a01 * sY0, c02 = a02 * sZ0;
    const float c10 = a10 * sY1 * sZ1, c11 = a11 * sY1, c12 = a12 * sZ1;
    const float cb  = a03 + a13;

    unsigned sz0 = 0, sz1 = 0;
    #pragma unroll
    for (int l = 0; l < 8; ++l) {
        sz0 |= ((zb[0][l] >> n) & 1u) << l;
        sz1 |= ((zb[1][l] >> n) & 1u) << l;
    }
    const float zc0 = 8.f - 2.f * (float)__popc(sz0);
    const float zc1 = 8.f - 2.f * (float)__popc(sz1);
    const float czc = c02 * zc0 + c12 * zc1 + cb;

    const int ybw = (mb >> 2);
    const int ybs = (mb & 3) * 8;

    #pragma unroll
    for (int q = 0; q < 4; ++q) {
        const int m = mb + 8 * q;
        const unsigned sy0 = (yb[0][2 * q + ybw] >> ybs) & 0xffu;
        const unsigned sy1 = (yb[1][2 * q + ybw] >> ybs) & 0xffu;
        const float w0  = 8.f - 2.f * (float)__popc(sy0 ^ sz0);
        const float w1  = 8.f - 2.f * (float)__popc(sy1 ^ sz1);
        const float ys0 = 8.f - 2.f * (float)__popc(sy0);
        const float ys1 = 8.f - 2.f * (float)__popc(sy1);
        const float acc = c00 * w0 + c01 * ys0 + c10 * w1 + c11 * ys1 + czc;
        wt[(size_t)(jj * 32 + m) * 1024 + kk * 32 + n] = f2bf(acc);
    }
}

// ---------------------------------------------------------------------------
// GEMM: out[2048,1024] = s * (Q x Wt^T) + bias
// 64(M) x 64(N) tile, grid (16,32)=512 blocks (2/CU), 4 waves 2x2,
// BK=128 (8 K-iters -> 8 barriers instead of 16), double-buffered LDS
// (2 x 32 KB), XOR-swizzled 16B chunks over 16 chunks/row:
//   chunk (row, kc) lives at row*16 + (kc ^ (row&15))
__global__ __launch_bounds__(256) void gemm_mfma(
    const unsigned short* __restrict__ qx,   // (2048,1024) bf16 bits
    const unsigned short* __restrict__ wt,   // (1024 N,1024 K) bf16 bits
    const float* __restrict__ bias,          // (1024)
    const float* __restrict__ act_scale,     // (1)
    float* __restrict__ out)                 // (2048,1024)
{
    // buffer = A 64x128 (16KB) + B 64x128 (16KB); double buffered = 64KB
    __shared__ __align__(16) short lds[2 * 16384];

    const int tid  = threadIdx.x;
    const int lane = tid & 63;
    const int wave = tid >> 6;
    const int wm = wave >> 1;
    const int wn = wave & 1;
    const int rowBase = blockIdx.y * 64;
    const int colBase = blockIdx.x * 64;

    const float s = fmaxf(fabsf(act_scale[0]), 1e-8f);

    f32x4 acc[2][2];
    #pragma unroll
    for (int i = 0; i < 2; ++i)
        #pragma unroll
        for (int jx = 0; jx < 2; ++jx)
            acc[i][jx] = (f32x4)0.f;

    // staging: panel = 64 rows x 16 chunks(16B). chunk c = g*64 + lane,
    // g = issue*4+wave (issue 0..3). row = g*4 + (lane>>4), slot = lane&15,
    // global k-chunk = slot ^ (row&15).
    const int lrow = lane >> 4;               // 0..3
    const int slot = lane & 15;
    const unsigned short* ag[4];
    const unsigned short* bg[4];
    #pragma unroll
    for (int is = 0; is < 4; ++is) {
        const int g   = is * 4 + wave;        // 0..15
        const int row = g * 4 + lrow;         // 0..63
        const int gk  = slot ^ (row & 15);
        ag[is] = qx + (size_t)(rowBase + row) * 1024 + gk * 8;
        bg[is] = wt + (size_t)(colBase + row) * 1024 + gk * 8;
    }

    char* const ldsc = (char*)lds;
    const int q4  = lane >> 4;
    const int l16 = lane & 15;

    // prologue: stage tile 0 into buffer 0 (A at 0, B at 16KB)
    #pragma unroll
    for (int is = 0; is < 4; ++is) {
        const int g = is * 4 + wave;
        gl2lds16(ag[is], ldsc + g * 1024);
        gl2lds16(bg[is], ldsc + 16384 + g * 1024);
    }

    for (int kt = 0; kt < 8; ++kt) {
        __syncthreads();   // buffer kt&1 ready (drains prev prefetch too)

        if (kt + 1 < 8) {
            const int k1 = (kt + 1) * 128;
            char* bb = ldsc + ((kt + 1) & 1) * 32768;
            #pragma unroll
            for (int is = 0; is < 4; ++is) {
                const int g = is * 4 + wave;
                gl2lds16(ag[is] + k1, bb + g * 1024);
                gl2lds16(bg[is] + k1, bb + 16384 + g * 1024);
            }
        }

        const short* As = lds + (kt & 1) * 16384;   // [row][16 slots] swizzled
        const short* Bs = As + 8192;

        #pragma unroll
        for (int k2 = 0; k2 < 4; ++k2) {
            const int kc = k2 * 4 + q4;            // chunk slot 0..15
            bf16x8 af[2], bfr[2];
            #pragma unroll
            for (int im = 0; im < 2; ++im) {
                const int r = wm * 32 + im * 16 + l16;
                af[im] = *(const bf16x8*)&As[r * 128 + ((kc ^ (r & 15)) << 3)];
            }
            #pragma unroll
            for (int in = 0; in < 2; ++in) {
                const int r = wn * 32 + in * 16 + l16;
                bfr[in] = *(const bf16x8*)&Bs[r * 128 + ((kc ^ (r & 15)) << 3)];
            }
            #pragma unroll
            for (int im = 0; im < 2; ++im)
                #pragma unroll
                for (int in = 0; in < 2; ++in)
                    acc[im][in] = __builtin_amdgcn_mfma_f32_16x16x32_bf16(
                        af[im], bfr[in], acc[im][in], 0, 0, 0);
        }
    }

    // epilogue: C/D layout col = lane&15, row = quad*4 + reg
    #pragma unroll
    for (int im = 0; im < 2; ++im) {
        #pragma unroll
        for (int in = 0; in < 2; ++in) {
            const int col = colBase + wn * 32 + in * 16 + l16;
            const float b = bias[col];
            #pragma unroll
            for (int r = 0; r < 4; ++r) {
                const int row = rowBase + wm * 32 + im * 16 + q4 * 4 + r;
                out[(size_t)row * 1024 + col] = s * acc[im][in][r] + b;
            }
        }
    }
}

extern "C" void kernel_launch(void* const* d_in, const int* in_sizes, int n_in,
                              void* d_out, int out_size, void* d_ws, size_t ws_size,
                              hipStream_t stream) {
    const float* x         = (const float*)d_in[0];  // (2,1024,1024)
    const float* Y_fp      = (const float*)d_in[1];  // (2,32,32,32,8)
    const float* Z_fp      = (const float*)d_in[2];  // (2,32,32,8,32)
    const float* A         = (const float*)d_in[3];  // (2,32,32,4)
    const float* bias      = (const float*)d_in[4];  // (1024)
    const float* act_scale = (const float*)d_in[5];  // (1)
    float* out = (float*)d_out;                      // (2048,1024)

    unsigned short* wtp = (unsigned short*)d_ws;                            // 2 MB
    unsigned short* qxp = (unsigned short*)((char*)d_ws + 2 * 1024 * 1024); // 4 MB

    fused_pre<<<dim3(1536), dim3(256), 0, stream>>>(Y_fp, Z_fp, A, x, act_scale, wtp, qxp);
    gemm_mfma<<<dim3(16, 32), dim3(256), 0, stream>>>(qxp, wtp, bias, act_scale, out);
}